// Round 10
// baseline (71.477 us; speedup 1.0000x reference)
//
#include <hip/hip_runtime.h>
#include <hip/hip_cooperative_groups.h>

namespace cg = cooperative_groups;

// x,y float32 (B=2, C=1, D=32, H=128, W=128).
// out = mean over [B,C,D,3,H,3,W,3] of |d_c - d_n|, d = x - y, zero-padded
// neighbors. Per voxel: sum |c - n| over all 27 zero-padded neighbors.
// Single COOPERATIVE dispatch: worker -> grid.sync() -> block-0 tail reduce.
constexpr int Dd = 32, Hh = 128, Ww = 128, Bv = 2;
constexpr int NVOX = Bv * Dd * Hh * Ww;     // 1,048,576
constexpr int BLK  = 256;

constexpr int TD = 2, TH = 4;               // tile 2 x 4 x 128 (full W rows)
constexpr int ZT = Dd / TD;                 // 16
constexpr int YT = Hh / TH;                 // 32
constexpr int NBLK = Bv * ZT * YT;          // 1024 blocks = 4/CU (co-resident)
constexpr int LSTR = 136;                   // floats/LDS row; k = w + 4 -> 16B-aligned f4
constexpr int RZ = TD + 2, RY = TH + 2;     // halo: z in [z0-1,z0+2], y in [y0-1,y0+4]
constexpr int NROWS = RZ * RY;              // 24
constexpr int NSLOT = LSTR / 4;             // 34 float4 slots per row
constexpr int NITEM = NROWS * NSLOT;        // 816

__global__ void __launch_bounds__(BLK)
cdl_coop(const float* __restrict__ xg, const float* __restrict__ yg,
         float* __restrict__ partials, float* __restrict__ out)
{
    __shared__ float lds[NROWS * LSTR];     // 13,056 B
    __shared__ float smem[BLK / 64];

    const int tid = threadIdx.x;
    // XCD-aware bijective swizzle (NBLK % 8 == 0)
    const int bid = (blockIdx.x & 7) * (NBLK / 8) + (blockIdx.x >> 3);

    int t = bid;
    const int yt  = t & (YT - 1); t >>= 5;
    const int zt  = t & (ZT - 1); t >>= 4;
    const int vol = t;
    const int z0 = zt * TD, y0 = yt * TH;
    const size_t vbase = (size_t)vol * Dd * Hh * Ww;

    // ---- stage d = x - y halo tile into LDS (zero outside volume / w-pad) ----
#pragma unroll
    for (int p = 0; p < 4; ++p) {
        const int idx = p * BLK + tid;
        if (idx < NITEM) {
            const int row  = idx / NSLOT;
            const int slot = idx - row * NSLOT;
            const int lzr  = row / RY;
            const int lyr  = row - lzr * RY;
            const int gz = z0 + lzr - 1;        // [z0-1, z0+2]
            const int gy = y0 + lyr - 1;        // [y0-1, y0+4]
            const int w  = 4 * slot - 4;        // float4 covers w..w+3
            float4 v = make_float4(0.f, 0.f, 0.f, 0.f);
            if ((unsigned)gz < (unsigned)Dd && (unsigned)gy < (unsigned)Hh &&
                (unsigned)w < (unsigned)Ww) {
                const size_t g = vbase + ((size_t)gz * Hh + gy) * Ww + w;
                const float4 a = *(const float4*)(xg + g);
                const float4 b = *(const float4*)(yg + g);
                v = make_float4(a.x - b.x, a.y - b.y, a.z - b.z, a.w - b.w);
            }
            *(float4*)&lds[row * LSTR + 4 * slot] = v;
        }
    }
    __syncthreads();

    // ---- compute: thread -> one (z,y) row, 4 voxels (w = 4j..4j+3) ----
    const int j  = tid & 31;                    // w-segment
    const int rr = tid >> 5;                    // 0..7
    const int lz = rr >> 2;                     // 0..1
    const int ly = rr & 3;                      // 0..3
    const int k0 = 4 * j + 4;

    const float* crow = &lds[((lz + 1) * RY + (ly + 1)) * LSTR + k0];
    const float4 c = *(const float4*)crow;

    float s = 0.f;
#pragma unroll
    for (int dz = 0; dz < 3; ++dz) {
#pragma unroll
        for (int dy = 0; dy < 3; ++dy) {
            const float* rp = &lds[((lz + dz) * RY + (ly + dy)) * LSTR + k0];
            const float4 A = *(const float4*)rp;
            const float  m = rp[-1];            // w-1 edge
            const float  q = rp[4];             // w+4 edge
            s += fabsf(c.x - m)   + fabsf(c.x - A.x) + fabsf(c.x - A.y);
            s += fabsf(c.y - A.x) + fabsf(c.y - A.y) + fabsf(c.y - A.z);
            s += fabsf(c.z - A.y) + fabsf(c.z - A.z) + fabsf(c.z - A.w);
            s += fabsf(c.w - A.z) + fabsf(c.w - A.w) + fabsf(c.w - q);
        }
    }

    // ---- block reduction, plain-store publish ----
    const int lane = tid & 63;
    const int wid  = tid >> 6;
#pragma unroll
    for (int off = 32; off > 0; off >>= 1) s += __shfl_down(s, off, 64);
    if (lane == 0) smem[wid] = s;
    __syncthreads();
    if (tid == 0)
        partials[bid] = smem[0] + smem[1] + smem[2] + smem[3];

    // ---- grid-wide barrier (runtime handles cross-XCD visibility) ----
    cg::this_grid().sync();

    // ---- tail reduce on one block ----
    if (blockIdx.x == 0) {
        float acc = 0.f;
#pragma unroll
        for (int i = 0; i < NBLK / BLK; ++i)
            acc += partials[i * BLK + tid];
#pragma unroll
        for (int off = 32; off > 0; off >>= 1) acc += __shfl_down(acc, off, 64);
        if (lane == 0) smem[wid] = acc;
        __syncthreads();
        if (tid == 0) {
            const double tot = (double)smem[0] + (double)smem[1] +
                               (double)smem[2] + (double)smem[3];
            out[0] = (float)(tot / (27.0 * (double)NVOX));
        }
    }
}

extern "C" void kernel_launch(void* const* d_in, const int* in_sizes, int n_in,
                              void* d_out, int out_size, void* d_ws, size_t ws_size,
                              hipStream_t stream) {
    const float* x  = (const float*)d_in[0];
    const float* y  = (const float*)d_in[1];
    float* partials = (float*)d_ws;           // NBLK floats
    float* out      = (float*)d_out;

    void* args[] = { (void*)&x, (void*)&y, (void*)&partials, (void*)&out };
    hipLaunchCooperativeKernel((const void*)cdl_coop, dim3(NBLK), dim3(BLK),
                               args, 0, stream);
}

// Round 11
// 12.322 us; speedup vs baseline: 5.8009x; 5.8009x over previous
//
#include <hip/hip_runtime.h>

// x,y float32 (B=2, C=1, D=32, H=128, W=128).
// out = mean over [B,C,D,3,H,3,W,3] of |d_c - d_n|, d = x - y, zero-padded
// neighbors. Per voxel: sum |c - n| over all 27 zero-padded neighbors.
// Two dispatches (proven structure). Worker: BLK=512, 2 voxels/thread ->
// 32 waves/CU (max occupancy); all LDS reads are 64-lane stride-8B b64
// patterns (2 lanes/bank = conflict-free per m136).
constexpr int Dd = 32, Hh = 128, Ww = 128, Bv = 2;
constexpr int NVOX = Bv * Dd * Hh * Ww;     // 1,048,576
constexpr int BLK  = 512;                   // 8 waves/block
constexpr int BLKF = 256;

constexpr int TD = 2, TH = 4;               // tile 2 x 4 x 128 (full W rows)
constexpr int ZT = Dd / TD;                 // 16
constexpr int YT = Hh / TH;                 // 32
constexpr int NBLK = Bv * ZT * YT;          // 1024 blocks = 4/CU = 32 waves/CU
constexpr int LSTR = 136;                   // floats/LDS row; k = w + 4
constexpr int RZ = TD + 2, RY = TH + 2;     // halo: z in [z0-1,z0+2], y in [y0-1,y0+4]
constexpr int NROWS = RZ * RY;              // 24
constexpr int NF2   = LSTR / 2;             // 68 float2 slots per row
constexpr int NITEM = NROWS * NF2;          // 1632

__global__ void __launch_bounds__(BLK, 8)
cdl_worker(const float* __restrict__ xg, const float* __restrict__ yg,
           float* __restrict__ partials)
{
    __shared__ float lds[NROWS * LSTR];     // 13,056 B
    __shared__ float smem[BLK / 64];

    const int tid = threadIdx.x;
    // XCD-aware bijective swizzle (NBLK % 8 == 0)
    const int bid = (blockIdx.x & 7) * (NBLK / 8) + (blockIdx.x >> 3);

    int t = bid;
    const int yt  = t & (YT - 1); t >>= 5;
    const int zt  = t & (ZT - 1); t >>= 4;
    const int vol = t;
    const int z0 = zt * TD, y0 = yt * TH;
    const size_t vbase = (size_t)vol * Dd * Hh * Ww;

    // ---- stage d = x - y halo tile into LDS (zero outside volume / w-pad) ----
    // float2 granularity: slot s covers k = 2s, 2s+1  ->  w = 2s-4, 2s-3.
#pragma unroll
    for (int p = 0; p < 4; ++p) {
        const int idx = p * BLK + tid;
        if (idx < NITEM) {
            const int row  = idx / NF2;
            const int slot = idx - row * NF2;
            const int lzr  = row / RY;
            const int lyr  = row - lzr * RY;
            const int gz = z0 + lzr - 1;        // [z0-1, z0+2]
            const int gy = y0 + lyr - 1;        // [y0-1, y0+4]
            const int w  = 2 * slot - 4;        // even; float2 covers w, w+1
            float2 v = make_float2(0.f, 0.f);
            if ((unsigned)gz < (unsigned)Dd && (unsigned)gy < (unsigned)Hh &&
                (unsigned)w <= 126u) {
                const size_t g = vbase + ((size_t)gz * Hh + gy) * Ww + w;
                const float2 a = *(const float2*)(xg + g);
                const float2 b = *(const float2*)(yg + g);
                v = make_float2(a.x - b.x, a.y - b.y);
            }
            *(float2*)&lds[row * LSTR + 2 * slot] = v;
        }
    }
    __syncthreads();

    // ---- compute: wave -> one (z,y) row; lane j -> voxels w = 2j, 2j+1 ----
    const int j  = tid & 63;                    // w-pair index
    const int r  = tid >> 6;                    // 0..7 (wave id)
    const int lz = r >> 2;                      // 0..1
    const int ly = r & 3;                       // 0..3
    const int k0 = 2 * j + 4;

    const float2 c = *(const float2*)&lds[((lz + 1) * RY + (ly + 1)) * LSTR + k0];

    float s = 0.f;
#pragma unroll
    for (int dz = 0; dz < 3; ++dz) {
#pragma unroll
        for (int dy = 0; dy < 3; ++dy) {
            const float* rp = &lds[((lz + dz) * RY + (ly + dy)) * LSTR];
            const float2 M = *(const float2*)&rp[k0 - 2];   // M.y = w-1
            const float2 A = *(const float2*)&rp[k0];       // w, w+1
            const float2 Q = *(const float2*)&rp[k0 + 2];   // Q.x = w+2
            s += fabsf(c.x - M.y) + fabsf(c.x - A.x) + fabsf(c.x - A.y);
            s += fabsf(c.y - A.x) + fabsf(c.y - A.y) + fabsf(c.y - Q.x);
        }
    }

    // ---- block reduction, plain-store publish (flushed at kernel end) ----
    const int lane = tid & 63;
    const int wid  = tid >> 6;
#pragma unroll
    for (int off = 32; off > 0; off >>= 1) s += __shfl_down(s, off, 64);
    if (lane == 0) smem[wid] = s;
    __syncthreads();
    if (tid == 0) {
        float tsum = 0.f;
#pragma unroll
        for (int w = 0; w < BLK / 64; ++w) tsum += smem[w];
        partials[bid] = tsum;
    }
}

__global__ void __launch_bounds__(BLKF)
cdl_finish(const float* __restrict__ partials, float* __restrict__ out)
{
    float acc = 0.f;
#pragma unroll
    for (int i = 0; i < NBLK / BLKF; ++i)
        acc += partials[i * BLKF + threadIdx.x];
#pragma unroll
    for (int off = 32; off > 0; off >>= 1) acc += __shfl_down(acc, off, 64);

    __shared__ float smem[BLKF / 64];
    const int lane = threadIdx.x & 63;
    const int wid  = threadIdx.x >> 6;
    if (lane == 0) smem[wid] = acc;
    __syncthreads();
    if (threadIdx.x == 0) {
        const double tot = (double)smem[0] + (double)smem[1] +
                           (double)smem[2] + (double)smem[3];
        out[0] = (float)(tot / (27.0 * (double)NVOX));
    }
}

extern "C" void kernel_launch(void* const* d_in, const int* in_sizes, int n_in,
                              void* d_out, int out_size, void* d_ws, size_t ws_size,
                              hipStream_t stream) {
    const float* x  = (const float*)d_in[0];
    const float* y  = (const float*)d_in[1];
    float* partials = (float*)d_ws;           // NBLK floats
    float* out      = (float*)d_out;

    cdl_worker<<<NBLK, BLK, 0, stream>>>(x, y, partials);
    cdl_finish<<<1, BLKF, 0, stream>>>(partials, out);
}